// Round 1
// baseline (2068.003 us; speedup 1.0000x reference)
//
#include <hip/hip_runtime.h>
#include <hip/hip_bf16.h>
#include <math.h>

#define B_ 16
#define T_ 512
#define H_ 768
#define S_ 32
#define L_ 50
#define NT_ 3
#define HS_ 3072

// ---------------------------------------------------------------------------
// 1) prefix sums over T:  pre[b, t, :] = sum_{t' < t} h[b, t', :],  (B, T+1, H)
// ---------------------------------------------------------------------------
__global__ __launch_bounds__(256) void cumsum_kernel(const float* __restrict__ h,
                                                     float* __restrict__ pre) {
    int t = blockIdx.x * blockDim.x + threadIdx.x;   // 0 .. B*H-1
    int b = t / H_, hd = t % H_;
    const float* hp = h + (size_t)b * T_ * H_ + hd;
    float* pp = pre + (size_t)b * (T_ + 1) * H_ + hd;
    float acc = 0.f;
    pp[0] = 0.f;
#pragma unroll 8
    for (int tt = 0; tt < T_; tt++) {
        acc += hp[(size_t)tt * H_];
        pp[(size_t)(tt + 1) * H_] = acc;
    }
}

// ---------------------------------------------------------------------------
// 2) gather rows for the span-start GEMM (512 rows) and cls GEMM (16 rows)
//    G: (528, H) ; rows [0,512): h[b, clip(start)] ; rows [512,528): h[b, 0]
// ---------------------------------------------------------------------------
__global__ void gather_kernel(const float* __restrict__ h,
                              const int* __restrict__ starts,
                              float* __restrict__ G) {
    int r = blockIdx.x;
    int src_row;
    if (r < B_ * S_) {
        int b = r / S_;
        int sv = starts[r];
        int sc = min(max(sv, 0), T_ - 1);
        src_row = b * T_ + sc;
    } else {
        int b = r - B_ * S_;
        src_row = b * T_;
    }
    for (int j = threadIdx.x; j < H_; j += 256)
        G[(size_t)r * H_ + j] = h[(size_t)src_row * H_ + j];
}

// ---------------------------------------------------------------------------
// 3) generic fp32 GEMM: C[M, 3072] = A[M, 768] @ Wp[768, 3072]
//    BM=128, BN=64, BK=16; 256 threads; 8x4 micro-tile per thread.
// ---------------------------------------------------------------------------
__device__ inline void store_out(float* p, float v) { *p = v; }
__device__ inline void store_out(__hip_bfloat16* p, float v) { *p = __float2bfloat16(v); }

template <typename OutT>
__global__ __launch_bounds__(256) void gemm768(const float* __restrict__ A, int M,
                                               const float* __restrict__ Wp,
                                               OutT* __restrict__ C) {
    const int K = 768;
    __shared__ float As[16][128 + 1];
    __shared__ float Bs[16][64 + 1];
    int n0 = blockIdx.x * 64;
    int m0 = blockIdx.y * 128;
    int tid = threadIdx.x;
    int tx = tid % 16;        // -> 4 cols
    int ty = tid / 16;        // -> 8 rows
    float acc[8][4] = {};
    for (int k0 = 0; k0 < K; k0 += 16) {
        // A tile: 128 x 16 (2048 elems, 8/thread)
#pragma unroll
        for (int i = 0; i < 8; i++) {
            int m_l = (tid / 16) + i * 16;
            int k_l = tid % 16;
            int m = m0 + m_l;
            As[k_l][m_l] = (m < M) ? A[(size_t)m * 768 + k0 + k_l] : 0.f;
        }
        // W tile: 16 x 64 (1024 elems, 4/thread), coalesced 64-wide
#pragma unroll
        for (int i = 0; i < 4; i++) {
            int k_l = (tid / 64) + i * 4;
            int n_l = tid % 64;
            Bs[k_l][n_l] = Wp[(size_t)(k0 + k_l) * HS_ + n0 + n_l];
        }
        __syncthreads();
#pragma unroll
        for (int kk = 0; kk < 16; kk++) {
            float a[8], bb[4];
#pragma unroll
            for (int i = 0; i < 8; i++) a[i] = As[kk][ty * 8 + i];
#pragma unroll
            for (int j = 0; j < 4; j++) bb[j] = Bs[kk][tx * 4 + j];
#pragma unroll
            for (int i = 0; i < 8; i++)
#pragma unroll
                for (int j = 0; j < 4; j++) acc[i][j] += a[i] * bb[j];
        }
        __syncthreads();
    }
#pragma unroll
    for (int i = 0; i < 8; i++) {
        int m = m0 + ty * 8 + i;
        if (m < M) {
#pragma unroll
            for (int j = 0; j < 4; j++)
                store_out(&C[(size_t)m * HS_ + n0 + tx * 4 + j], acc[i][j]);
        }
    }
}

// ---------------------------------------------------------------------------
// 4) combine: per (b,s) block -> scores[b,s,l] for all l, type logits at l==gi
// ---------------------------------------------------------------------------
__global__ __launch_bounds__(256) void combine_kernel(
    const float* __restrict__ ST, const float* __restrict__ CC,
    const float* __restrict__ b1,
    const __hip_bfloat16* __restrict__ X, const __hip_bfloat16* __restrict__ Y,
    const float* __restrict__ w_score, const float* __restrict__ b_score,
    const float* __restrict__ W_type,
    const int* __restrict__ starts, const int* __restrict__ ends,
    float* __restrict__ scores, float* __restrict__ tgold) {
    __shared__ float c0[HS_];
    __shared__ float wred[4];
    __shared__ float tred[3][4];
    int bs = blockIdx.x;
    int b = bs / S_;
    int tid = threadIdx.x;
    int sv = starts[bs], ev = ends[bs];
    int gi = min(max(ev - sv, 0), L_ - 1);
    int sc = min(max(sv, 0), T_ - 1);
    for (int j = tid; j < HS_; j += 256)
        c0[j] = ST[(size_t)bs * HS_ + j] + CC[(size_t)b * HS_ + j] + b1[j];
    float bs0 = b_score[0];
    __syncthreads();
    const __hip_bfloat16* Ys = Y + (size_t)(b * (T_ + 1) + sc) * HS_;
    float tacc0 = 0.f, tacc1 = 0.f, tacc2 = 0.f;
    for (int l = 0; l < L_; l++) {
        int p = sv + l;
        int pc = min(max(p, 0), T_ - 1);
        float invlen = 1.0f / (float)(l + 1);   // seg_len = max(p-s+1,1) = l+1
        const __hip_bfloat16* Xr = X + (size_t)(b * T_ + pc) * HS_;
        const __hip_bfloat16* Yp = Y + (size_t)(b * (T_ + 1) + pc + 1) * HS_;
        float local = 0.f;
        bool isg = (l == gi);
#pragma unroll
        for (int j = 0; j < HS_ / 256; j++) {
            int d = tid + j * 256;
            float v = c0[d] + __bfloat162float(Xr[d]) +
                      (__bfloat162float(Yp[d]) - __bfloat162float(Ys[d])) * invlen;
            float g = 0.5f * v * (1.0f + erff(v * 0.70710678118654752f));
            local += g * w_score[d];
            if (isg) {
                tacc0 += g * W_type[d * NT_ + 0];
                tacc1 += g * W_type[d * NT_ + 1];
                tacc2 += g * W_type[d * NT_ + 2];
            }
        }
        for (int off = 32; off >= 1; off >>= 1) local += __shfl_down(local, off);
        if ((tid & 63) == 0) wred[tid >> 6] = local;
        __syncthreads();
        if (tid == 0)
            scores[(size_t)bs * L_ + l] = wred[0] + wred[1] + wred[2] + wred[3] + bs0;
        __syncthreads();
    }
    for (int off = 32; off >= 1; off >>= 1) {
        tacc0 += __shfl_down(tacc0, off);
        tacc1 += __shfl_down(tacc1, off);
        tacc2 += __shfl_down(tacc2, off);
    }
    if ((tid & 63) == 0) {
        int w = tid >> 6;
        tred[0][w] = tacc0; tred[1][w] = tacc1; tred[2][w] = tacc2;
    }
    __syncthreads();
    if (tid < NT_)
        tgold[(size_t)bs * NT_ + tid] =
            tred[tid][0] + tred[tid][1] + tred[tid][2] + tred[tid][3];
}

// ---------------------------------------------------------------------------
// 5) final loss: one block, one thread per (b,s)
// ---------------------------------------------------------------------------
__global__ __launch_bounds__(512) void loss_kernel(
    const float* __restrict__ scores, const float* __restrict__ tgold,
    const int* __restrict__ mask, const int* __restrict__ starts,
    const int* __restrict__ ends, const int* __restrict__ types,
    const float* __restrict__ b_type, float* __restrict__ out) {
    __shared__ int svl[B_];
    __shared__ float r[3][8];
    int tid = threadIdx.x;                 // 0..511 == (b,s)
    int b = tid / S_;
    if (tid < B_) svl[tid] = 0;
    __syncthreads();
    {   // cooperative valid_len: thread tid sums mask[tid*16 .. +16) (all in b=tid/32)
        int part = 0;
        const int* mp = mask + tid * 16;
#pragma unroll
        for (int i = 0; i < 16; i++) part += mp[i];
        atomicAdd(&svl[tid / (T_ / 16)], part);
    }
    __syncthreads();
    int vl = svl[b];
    int lt = max(1, vl - 2);
    int sv = starts[tid], ev = ends[tid];
    int gold = ev - sv;
    bool valid = (sv >= 1) && (sv <= lt) && (ev >= sv) && (ev <= lt) && (gold < L_);
    int emax = min(sv + L_ - 1, lt);
    const float* sp = scores + (size_t)tid * L_;
    float m = -1e30f;
    for (int l = 0; l < L_; l++) {
        float v = (sv + l <= emax) ? sp[l] : -1e9f;
        m = fmaxf(m, v);
    }
    float sum = 0.f;
    for (int l = 0; l < L_; l++) {
        float v = (sv + l <= emax) ? sp[l] : -1e9f;
        sum += expf(v - m);
    }
    int gi = min(max(gold, 0), L_ - 1);
    float vg = (sv + gi <= emax) ? sp[gi] : -1e9f;
    float end_loss = (m + logf(sum)) - vg;

    float t0 = tgold[tid * 3 + 0] + b_type[0];
    float t1 = tgold[tid * 3 + 1] + b_type[1];
    float t2 = tgold[tid * 3 + 2] + b_type[2];
    float tm = fmaxf(t0, fmaxf(t1, t2));
    float tsum = expf(t0 - tm) + expf(t1 - tm) + expf(t2 - tm);
    int tg = min(max(types[tid], 0), NT_ - 1);
    float tv = (tg == 0) ? t0 : ((tg == 1) ? t1 : t2);
    float type_loss = (tm + logf(tsum)) - tv;

    float ve = valid ? end_loss : 0.f;
    float vt = valid ? type_loss : 0.f;
    float vc = valid ? 1.f : 0.f;
    for (int off = 32; off >= 1; off >>= 1) {
        ve += __shfl_down(ve, off);
        vt += __shfl_down(vt, off);
        vc += __shfl_down(vc, off);
    }
    if ((tid & 63) == 0) {
        int w = tid >> 6;
        r[0][w] = ve; r[1][w] = vt; r[2][w] = vc;
    }
    __syncthreads();
    if (tid == 0) {
        float se = 0, st = 0, n = 0;
        for (int w = 0; w < 8; w++) { se += r[0][w]; st += r[1][w]; n += r[2][w]; }
        float denom = fmaxf(n, 1.f);
        out[0] = (n > 0.f) ? (se / denom + st / denom) : 0.f;
    }
}

// ---------------------------------------------------------------------------
extern "C" void kernel_launch(void* const* d_in, const int* in_sizes, int n_in,
                              void* d_out, int out_size, void* d_ws, size_t ws_size,
                              hipStream_t stream) {
    const float* h       = (const float*)d_in[0];
    const int*   mask    = (const int*)d_in[1];
    const int*   starts  = (const int*)d_in[2];
    const int*   ends    = (const int*)d_in[3];
    const int*   types   = (const int*)d_in[4];
    const float* W1      = (const float*)d_in[5];
    const float* b1      = (const float*)d_in[6];
    const float* w_score = (const float*)d_in[7];
    const float* b_score = (const float*)d_in[8];
    const float* W_type  = (const float*)d_in[9];
    const float* b_type  = (const float*)d_in[10];
    float* out = (float*)d_out;

    char* ws = (char*)d_ws;
    size_t off = 0;
    float* pre = (float*)(ws + off);            off += (size_t)B_ * (T_ + 1) * H_ * 4;
    __hip_bfloat16* X = (__hip_bfloat16*)(ws + off); off += (size_t)B_ * T_ * HS_ * 2;
    __hip_bfloat16* Y = (__hip_bfloat16*)(ws + off); off += (size_t)B_ * (T_ + 1) * HS_ * 2;
    float* G      = (float*)(ws + off);         off += (size_t)(B_ * S_ + B_) * H_ * 4;
    float* ST     = (float*)(ws + off);         off += (size_t)B_ * S_ * HS_ * 4;
    float* CC     = (float*)(ws + off);         off += (size_t)B_ * HS_ * 4;
    float* scores = (float*)(ws + off);         off += (size_t)B_ * S_ * L_ * 4;
    float* tgold  = (float*)(ws + off);         off += (size_t)B_ * S_ * NT_ * 4;

    hipLaunchKernelGGL(cumsum_kernel, dim3((B_ * H_) / 256), dim3(256), 0, stream, h, pre);
    hipLaunchKernelGGL(gather_kernel, dim3(B_ * S_ + B_), dim3(256), 0, stream, h, starts, G);
    // ST = G[0:512] @ W1[0:768]
    hipLaunchKernelGGL((gemm768<float>), dim3(48, 4), dim3(256), 0, stream,
                       G, B_ * S_, W1, ST);
    // CC = G[512:528] @ W1[2304:3072]
    hipLaunchKernelGGL((gemm768<float>), dim3(48, 1), dim3(256), 0, stream,
                       G + (size_t)(B_ * S_) * H_, B_, W1 + (size_t)2304 * HS_, CC);
    // X = h @ W1[768:1536]   (M = 8192)
    hipLaunchKernelGGL((gemm768<__hip_bfloat16>), dim3(48, 64), dim3(256), 0, stream,
                       h, B_ * T_, W1 + (size_t)768 * HS_, X);
    // Y = pre @ W1[1536:2304]  (M = 8208)
    hipLaunchKernelGGL((gemm768<__hip_bfloat16>), dim3(48, 65), dim3(256), 0, stream,
                       pre, B_ * (T_ + 1), W1 + (size_t)1536 * HS_, Y);
    hipLaunchKernelGGL(combine_kernel, dim3(B_ * S_), dim3(256), 0, stream,
                       ST, CC, b1, X, Y, w_score, b_score, W_type, starts, ends,
                       scores, tgold);
    hipLaunchKernelGGL(loss_kernel, dim3(1), dim3(512), 0, stream,
                       scores, tgold, mask, starts, ends, types, b_type, out);
}

// Round 2
// 474.072 us; speedup vs baseline: 4.3622x; 4.3622x over previous
//
#include <hip/hip_runtime.h>
#include <hip/hip_bf16.h>
#include <math.h>

#define B_ 16
#define T_ 512
#define H_ 768
#define S_ 32
#define L_ 50
#define NT_ 3
#define HS_ 3072
#define CH_ 8
#define CT_ 64  // T_/CH_

typedef __attribute__((ext_vector_type(8))) short short8;
typedef __attribute__((ext_vector_type(4))) float float4v;

__device__ __forceinline__ unsigned short f2bf(float f) {
    __hip_bfloat16 b = __float2bfloat16(f);
    return *(unsigned short*)&b;
}
__device__ __forceinline__ float bf2f(unsigned short u) {
    union { unsigned int i; float f; } v; v.i = ((unsigned int)u) << 16; return v.f;
}
__device__ __forceinline__ void load_lds16(const void* g, void* l) {
    __builtin_amdgcn_global_load_lds((__attribute__((address_space(1))) void*)g,
                                     (__attribute__((address_space(3))) void*)l, 16, 0, 0);
}

// ---------------------------------------------------------------------------
// chunked cumsum: pass1 partial sums, pass2 prefix over chunks, pass3 emit bf16
// ---------------------------------------------------------------------------
__global__ __launch_bounds__(256) void cumsum_pass1(const float* __restrict__ h,
                                                    float* __restrict__ partial) {
    int idx = blockIdx.x * 256 + threadIdx.x;        // (b, ch, hd)
    int hd = idx % H_; int t = idx / H_; int ch = t % CH_; int b = t / CH_;
    const float* hp = h + ((size_t)b * T_ + ch * CT_) * H_ + hd;
    float acc = 0.f;
#pragma unroll 8
    for (int tt = 0; tt < CT_; tt++) acc += hp[(size_t)tt * H_];
    partial[idx] = acc;
}

__global__ __launch_bounds__(256) void cumsum_pass2(float* __restrict__ partial) {
    int idx = blockIdx.x * 256 + threadIdx.x;        // (b, hd)
    int hd = idx % H_, b = idx / H_;
    float acc = 0.f;
#pragma unroll
    for (int ch = 0; ch < CH_; ch++) {
        size_t o = ((size_t)b * CH_ + ch) * H_ + hd;
        float v = partial[o];
        partial[o] = acc;
        acc += v;
    }
}

__global__ __launch_bounds__(256) void cumsum_pass3(const float* __restrict__ h,
                                                    const float* __restrict__ partial,
                                                    __hip_bfloat16* __restrict__ preb) {
    int idx = blockIdx.x * 256 + threadIdx.x;        // (b, ch, hd)
    int hd = idx % H_; int t = idx / H_; int ch = t % CH_; int b = t / CH_;
    float acc = partial[idx];
    const float* hp = h + ((size_t)b * T_ + ch * CT_) * H_ + hd;
    __hip_bfloat16* pp = preb + ((size_t)b * (T_ + 1) + ch * CT_ + 1) * H_ + hd;
    if (ch == 0) preb[((size_t)b * (T_ + 1)) * H_ + hd] = __float2bfloat16(0.f);
#pragma unroll 8
    for (int tt = 0; tt < CT_; tt++) {
        acc += hp[(size_t)tt * H_];
        pp[(size_t)tt * H_] = __float2bfloat16(acc);
    }
}

// ---------------------------------------------------------------------------
// h (fp32) -> hb (bf16), vectorized
// ---------------------------------------------------------------------------
__global__ __launch_bounds__(256) void convert_h(const float4* __restrict__ h4,
                                                 ushort4* __restrict__ hb4) {
    int i = blockIdx.x * 256 + threadIdx.x;
    float4 v = h4[i];
    ushort4 o;
    o.x = f2bf(v.x); o.y = f2bf(v.y); o.z = f2bf(v.z); o.w = f2bf(v.w);
    hb4[i] = o;
}

// ---------------------------------------------------------------------------
// gather span-start rows (512) + cls rows (16) into Gb (bf16), rows padded
// ---------------------------------------------------------------------------
__global__ void gather_kernel(const float* __restrict__ h,
                              const int* __restrict__ starts,
                              __hip_bfloat16* __restrict__ Gb) {
    int r = blockIdx.x;
    int src_row;
    if (r < B_ * S_) {
        int b = r / S_;
        int sv = starts[r];
        int sc = min(max(sv, 0), T_ - 1);
        src_row = b * T_ + sc;
    } else {
        int b = r - B_ * S_;
        src_row = b * T_;
    }
    for (int j = threadIdx.x; j < H_; j += 256)
        Gb[(size_t)r * H_ + j] = __float2bfloat16(h[(size_t)src_row * H_ + j]);
}

// ---------------------------------------------------------------------------
// W1 (3072x3072 fp32) -> 4 transposed bf16 panels Wt[p][n=3072][k=768]
// ---------------------------------------------------------------------------
__global__ __launch_bounds__(256) void transpose_w(const float* __restrict__ W1,
                                                   __hip_bfloat16* __restrict__ Wt) {
    __shared__ float tile[64][65];
    int n0 = blockIdx.x * 64, k0 = blockIdx.y * 64;
    int c = threadIdx.x & 63, r0 = threadIdx.x >> 6;
#pragma unroll
    for (int i = 0; i < 16; i++) {
        int r = r0 + i * 4;
        tile[r][c] = W1[(size_t)(k0 + r) * HS_ + n0 + c];
    }
    __syncthreads();
    int p = k0 / H_, kl = k0 % H_;
    __hip_bfloat16* out = Wt + (size_t)p * HS_ * H_;
#pragma unroll
    for (int i = 0; i < 16; i++) {
        int r = r0 + i * 4;
        out[(size_t)(n0 + r) * H_ + kl + c] = __float2bfloat16(tile[c][r]);
    }
}

// ---------------------------------------------------------------------------
// MFMA GEMM: C[M,3072] = A[M,768](bf16) @ Bt^T, Bt = [3072][768] bf16 (B^T)
// 128x128 tile, BK=32, 4 waves, 16x16x32 mfma, global_load_lds staging
// ---------------------------------------------------------------------------
__device__ inline void store_out(float* p, float v) { *p = v; }
__device__ inline void store_out(__hip_bfloat16* p, float v) { *p = __float2bfloat16(v); }

template <typename OutT>
__global__ __launch_bounds__(256) void mfma_gemm(const __hip_bfloat16* __restrict__ A,
                                                 int M,
                                                 const __hip_bfloat16* __restrict__ Bt,
                                                 OutT* __restrict__ C) {
    constexpr int K = H_;
    __shared__ __hip_bfloat16 As[128 * 32];
    __shared__ __hip_bfloat16 Bs[128 * 32];
    int tid = threadIdx.x;
    int wave = tid >> 6, lane = tid & 63;
    int m0 = blockIdx.y * 128, n0 = blockIdx.x * 128;
    int wm = (wave & 1) * 64, wn = (wave >> 1) * 64;

    float4v acc[4][4] = {};

    int c1 = wave * 128 + lane;      // chunk ids staged by this lane
    int c2 = c1 + 64;
    int lr = lane & 15, lq = lane >> 4;

    for (int k0 = 0; k0 < K; k0 += 32) {
        __syncthreads();
        // stage A tile (128x32 bf16 = 512 x 16B chunks)
        load_lds16(A + (size_t)(m0 + (c1 >> 2)) * K + k0 + (c1 & 3) * 8,
                   &As[(size_t)(wave * 128) * 8]);
        load_lds16(A + (size_t)(m0 + (c2 >> 2)) * K + k0 + (c2 & 3) * 8,
                   &As[(size_t)(wave * 128 + 64) * 8]);
        // stage B tile
        load_lds16(Bt + (size_t)(n0 + (c1 >> 2)) * K + k0 + (c1 & 3) * 8,
                   &Bs[(size_t)(wave * 128) * 8]);
        load_lds16(Bt + (size_t)(n0 + (c2 >> 2)) * K + k0 + (c2 & 3) * 8,
                   &Bs[(size_t)(wave * 128 + 64) * 8]);
        __syncthreads();

        short8 af[4], bf[4];
        const short* Asp = (const short*)As;
        const short* Bsp = (const short*)Bs;
#pragma unroll
        for (int mi = 0; mi < 4; mi++)
            af[mi] = *(const short8*)&Asp[(wm + mi * 16 + lr) * 32 + lq * 8];
#pragma unroll
        for (int ni = 0; ni < 4; ni++)
            bf[ni] = *(const short8*)&Bsp[(wn + ni * 16 + lr) * 32 + lq * 8];
#pragma unroll
        for (int mi = 0; mi < 4; mi++)
#pragma unroll
            for (int ni = 0; ni < 4; ni++)
                acc[mi][ni] = __builtin_amdgcn_mfma_f32_16x16x32_bf16(
                    af[mi], bf[ni], acc[mi][ni], 0, 0, 0);
    }

    // epilogue: C/D layout col=lane&15, row=(lane>>4)*4+reg
    int col = lane & 15, rq = (lane >> 4) * 4;
#pragma unroll
    for (int mi = 0; mi < 4; mi++) {
#pragma unroll
        for (int ni = 0; ni < 4; ni++) {
#pragma unroll
            for (int r = 0; r < 4; r++) {
                int m = m0 + wm + mi * 16 + rq + r;
                if (m < M) {
                    int n = n0 + wn + ni * 16 + col;
                    store_out(&C[(size_t)m * HS_ + n], acc[mi][ni][r]);
                }
            }
        }
    }
}

// ---------------------------------------------------------------------------
// combine: per (b,s) block -> scores[b,s,l], type logits at l==gi
// ---------------------------------------------------------------------------
__global__ __launch_bounds__(256) void combine_kernel(
    const float* __restrict__ ST, const float* __restrict__ CC,
    const float* __restrict__ b1,
    const __hip_bfloat16* __restrict__ X, const __hip_bfloat16* __restrict__ Y,
    const float* __restrict__ w_score, const float* __restrict__ b_score,
    const float* __restrict__ W_type,
    const int* __restrict__ starts, const int* __restrict__ ends,
    float* __restrict__ scores, float* __restrict__ tgold) {
    __shared__ float c0[HS_];
    __shared__ float sw[HS_];
    __shared__ float ys[HS_];
    __shared__ float wred[4];
    __shared__ float tred[3][4];
    int bs = blockIdx.x;
    int b = bs / S_;
    int tid = threadIdx.x;
    int sv = starts[bs], ev = ends[bs];
    int gi = min(max(ev - sv, 0), L_ - 1);
    int sc = min(max(sv, 0), T_ - 1);
    const __hip_bfloat16* Ys = Y + (size_t)(b * (T_ + 1) + sc) * HS_;
    for (int j = tid; j < HS_; j += 256) {
        c0[j] = ST[(size_t)bs * HS_ + j] + CC[(size_t)b * HS_ + j] + b1[j];
        sw[j] = w_score[j];
        ys[j] = __bfloat162float(Ys[j]);
    }
    float bs0 = b_score[0];
    __syncthreads();
    float tacc0 = 0.f, tacc1 = 0.f, tacc2 = 0.f;
    for (int l = 0; l < L_; l++) {
        int p = sv + l;
        int pc = min(max(p, 0), T_ - 1);
        float invlen = 1.0f / (float)(l + 1);
        const ushort4* xr4 = (const ushort4*)(X + (size_t)(b * T_ + pc) * HS_);
        const ushort4* yp4 = (const ushort4*)(Y + (size_t)(b * (T_ + 1) + pc + 1) * HS_);
        float local = 0.f;
        bool isg = (l == gi);
#pragma unroll
        for (int j = 0; j < 3; j++) {
            int d4 = tid + j * 256;
            int d = d4 * 4;
            ushort4 xv = xr4[d4];
            ushort4 yv = yp4[d4];
            float xe[4] = {bf2f(xv.x), bf2f(xv.y), bf2f(xv.z), bf2f(xv.w)};
            float ye[4] = {bf2f(yv.x), bf2f(yv.y), bf2f(yv.z), bf2f(yv.w)};
#pragma unroll
            for (int q = 0; q < 4; q++) {
                float v = c0[d + q] + xe[q] + (ye[q] - ys[d + q]) * invlen;
                float g = 0.5f * v * (1.0f + erff(v * 0.70710678118654752f));
                local += g * sw[d + q];
                if (isg) {
                    tacc0 += g * W_type[(d + q) * NT_ + 0];
                    tacc1 += g * W_type[(d + q) * NT_ + 1];
                    tacc2 += g * W_type[(d + q) * NT_ + 2];
                }
            }
        }
        for (int off = 32; off >= 1; off >>= 1) local += __shfl_down(local, off);
        if ((tid & 63) == 0) wred[tid >> 6] = local;
        __syncthreads();
        if (tid == 0)
            scores[(size_t)bs * L_ + l] = wred[0] + wred[1] + wred[2] + wred[3] + bs0;
        __syncthreads();
    }
    for (int off = 32; off >= 1; off >>= 1) {
        tacc0 += __shfl_down(tacc0, off);
        tacc1 += __shfl_down(tacc1, off);
        tacc2 += __shfl_down(tacc2, off);
    }
    if ((tid & 63) == 0) {
        int w = tid >> 6;
        tred[0][w] = tacc0; tred[1][w] = tacc1; tred[2][w] = tacc2;
    }
    __syncthreads();
    if (tid < NT_)
        tgold[(size_t)bs * NT_ + tid] =
            tred[tid][0] + tred[tid][1] + tred[tid][2] + tred[tid][3];
}

// ---------------------------------------------------------------------------
// final loss: one block, one thread per (b,s)
// ---------------------------------------------------------------------------
__global__ __launch_bounds__(512) void loss_kernel(
    const float* __restrict__ scores, const float* __restrict__ tgold,
    const int* __restrict__ mask, const int* __restrict__ starts,
    const int* __restrict__ ends, const int* __restrict__ types,
    const float* __restrict__ b_type, float* __restrict__ out) {
    __shared__ int svl[B_];
    __shared__ float r[3][8];
    int tid = threadIdx.x;
    int b = tid / S_;
    if (tid < B_) svl[tid] = 0;
    __syncthreads();
    {
        int part = 0;
        const int* mp = mask + tid * 16;
#pragma unroll
        for (int i = 0; i < 16; i++) part += mp[i];
        atomicAdd(&svl[tid / (T_ / 16)], part);
    }
    __syncthreads();
    int vl = svl[b];
    int lt = max(1, vl - 2);
    int sv = starts[tid], ev = ends[tid];
    int gold = ev - sv;
    bool valid = (sv >= 1) && (sv <= lt) && (ev >= sv) && (ev <= lt) && (gold < L_);
    int emax = min(sv + L_ - 1, lt);
    const float* sp = scores + (size_t)tid * L_;
    float m = -1e30f;
    for (int l = 0; l < L_; l++) {
        float v = (sv + l <= emax) ? sp[l] : -1e9f;
        m = fmaxf(m, v);
    }
    float sum = 0.f;
    for (int l = 0; l < L_; l++) {
        float v = (sv + l <= emax) ? sp[l] : -1e9f;
        sum += expf(v - m);
    }
    int gi = min(max(gold, 0), L_ - 1);
    float vg = (sv + gi <= emax) ? sp[gi] : -1e9f;
    float end_loss = (m + logf(sum)) - vg;

    float t0 = tgold[tid * 3 + 0] + b_type[0];
    float t1 = tgold[tid * 3 + 1] + b_type[1];
    float t2 = tgold[tid * 3 + 2] + b_type[2];
    float tm = fmaxf(t0, fmaxf(t1, t2));
    float tsum = expf(t0 - tm) + expf(t1 - tm) + expf(t2 - tm);
    int tg = min(max(types[tid], 0), NT_ - 1);
    float tv = (tg == 0) ? t0 : ((tg == 1) ? t1 : t2);
    float type_loss = (tm + logf(tsum)) - tv;

    float ve = valid ? end_loss : 0.f;
    float vt = valid ? type_loss : 0.f;
    float vc = valid ? 1.f : 0.f;
    for (int off = 32; off >= 1; off >>= 1) {
        ve += __shfl_down(ve, off);
        vt += __shfl_down(vt, off);
        vc += __shfl_down(vc, off);
    }
    if ((tid & 63) == 0) {
        int w = tid >> 6;
        r[0][w] = ve; r[1][w] = vt; r[2][w] = vc;
    }
    __syncthreads();
    if (tid == 0) {
        float se = 0, st = 0, n = 0;
        for (int w = 0; w < 8; w++) { se += r[0][w]; st += r[1][w]; n += r[2][w]; }
        float denom = fmaxf(n, 1.f);
        out[0] = (n > 0.f) ? (se / denom + st / denom) : 0.f;
    }
}

// ---------------------------------------------------------------------------
extern "C" void kernel_launch(void* const* d_in, const int* in_sizes, int n_in,
                              void* d_out, int out_size, void* d_ws, size_t ws_size,
                              hipStream_t stream) {
    const float* h       = (const float*)d_in[0];
    const int*   mask    = (const int*)d_in[1];
    const int*   starts  = (const int*)d_in[2];
    const int*   ends    = (const int*)d_in[3];
    const int*   types   = (const int*)d_in[4];
    const float* W1      = (const float*)d_in[5];
    const float* b1      = (const float*)d_in[6];
    const float* w_score = (const float*)d_in[7];
    const float* b_score = (const float*)d_in[8];
    const float* W_type  = (const float*)d_in[9];
    const float* b_type  = (const float*)d_in[10];
    float* out = (float*)d_out;

    char* ws = (char*)d_ws;
    size_t off = 0;
    // X first so the small cumsum scratch can alias into it (X written later)
    __hip_bfloat16* X    = (__hip_bfloat16*)(ws + off); off += (size_t)8192 * HS_ * 2;
    __hip_bfloat16* Y    = (__hip_bfloat16*)(ws + off); off += (size_t)8208 * HS_ * 2;
    __hip_bfloat16* preb = (__hip_bfloat16*)(ws + off); off += (size_t)8320 * H_ * 2;   // padded
    __hip_bfloat16* hb   = (__hip_bfloat16*)(ws + off); off += (size_t)8192 * H_ * 2;
    __hip_bfloat16* Gb   = (__hip_bfloat16*)(ws + off); off += (size_t)640 * H_ * 2;    // padded
    __hip_bfloat16* Wt   = (__hip_bfloat16*)(ws + off); off += (size_t)4 * HS_ * H_ * 2;
    float* ST     = (float*)(ws + off);         off += (size_t)B_ * S_ * HS_ * 4;
    float* CC     = (float*)(ws + off);         off += (size_t)B_ * HS_ * 4;
    float* scores = (float*)(ws + off);         off += (size_t)B_ * S_ * L_ * 4;
    float* tgold  = (float*)(ws + off);         off += (size_t)B_ * S_ * NT_ * 4;
    float* partial = (float*)X;                 // aliases X, dead before X GEMM

    hipLaunchKernelGGL(cumsum_pass1, dim3(B_ * CH_ * H_ / 256), dim3(256), 0, stream, h, partial);
    hipLaunchKernelGGL(cumsum_pass2, dim3(B_ * H_ / 256), dim3(256), 0, stream, partial);
    hipLaunchKernelGGL(cumsum_pass3, dim3(B_ * CH_ * H_ / 256), dim3(256), 0, stream, h, partial, preb);
    hipLaunchKernelGGL(convert_h, dim3(8192 * H_ / 4 / 256), dim3(256), 0, stream,
                       (const float4*)h, (ushort4*)hb);
    hipLaunchKernelGGL(gather_kernel, dim3(B_ * S_ + B_), dim3(256), 0, stream, h, starts, Gb);
    hipLaunchKernelGGL(transpose_w, dim3(48, 48), dim3(256), 0, stream, W1, Wt);

    const __hip_bfloat16* WtST = Wt;                              // panel 0 (h_start)
    const __hip_bfloat16* WtX  = Wt + (size_t)1 * HS_ * H_;       // panel 1 (h_end)
    const __hip_bfloat16* WtY  = Wt + (size_t)2 * HS_ * H_;       // panel 2 (h_mean)
    const __hip_bfloat16* WtCC = Wt + (size_t)3 * HS_ * H_;       // panel 3 (cls)

    hipLaunchKernelGGL((mfma_gemm<__hip_bfloat16>), dim3(24, 64), dim3(256), 0, stream,
                       hb, 8192, WtX, X);
    hipLaunchKernelGGL((mfma_gemm<__hip_bfloat16>), dim3(24, 65), dim3(256), 0, stream,
                       preb, 8208, WtY, Y);
    hipLaunchKernelGGL((mfma_gemm<float>), dim3(24, 4), dim3(256), 0, stream,
                       Gb, 512, WtST, ST);
    hipLaunchKernelGGL((mfma_gemm<float>), dim3(24, 1), dim3(256), 0, stream,
                       Gb + (size_t)512 * H_, 16, WtCC, CC);

    hipLaunchKernelGGL(combine_kernel, dim3(B_ * S_), dim3(256), 0, stream,
                       ST, CC, b1, X, Y, w_score, b_score, W_type, starts, ends,
                       scores, tgold);
    hipLaunchKernelGGL(loss_kernel, dim3(1), dim3(512), 0, stream,
                       scores, tgold, mask, starts, ends, types, b_type, out);
}

// Round 3
// 376.036 us; speedup vs baseline: 5.4995x; 1.2607x over previous
//
#include <hip/hip_runtime.h>
#include <hip/hip_bf16.h>
#include <math.h>

#define B_ 16
#define T_ 512
#define H_ 768
#define S_ 32
#define L_ 50
#define NT_ 3
#define HS_ 3072
#define CH_ 8
#define CT_ 64  // T_/CH_

// A-buffer row layout (bf16, 768 cols):
//   [0, 8192)        hb   = bf16(h), row b*512+t
//   [8192, 16512)    preb = bf16(cumsum), row 8192 + b*513 + t  (8208 valid, pad to 8320)
//   [16512, 17152)   Gb   = gathered span-start rows (512) + cls rows (16), pad to 640
// XY-buffer (bf16, 3072 cols): rows 0..16399 = [X rows | Y rows], same row ids as A.
#define XROWS 8192
#define YBASE 8192
#define GBASE 16512
#define XYROWS 16400
#define AROWS 17152

typedef __attribute__((ext_vector_type(8))) short short8;
typedef __attribute__((ext_vector_type(4))) float float4v;

__device__ __forceinline__ float bf2f(unsigned short u) {
    union { unsigned int i; float f; } v; v.i = ((unsigned int)u) << 16; return v.f;
}
__device__ __forceinline__ void load_lds16(const void* g, void* l) {
    __builtin_amdgcn_global_load_lds((__attribute__((address_space(1))) void*)g,
                                     (__attribute__((address_space(3))) void*)l, 16, 0, 0);
}

// branch-free exact-gelu: Abramowitz-Stegun 3-term erf, max err 2.5e-5
__device__ __forceinline__ float gelu_exact(float v) {
    float a = fabsf(v) * 0.70710678118654752f;
    float t = __builtin_amdgcn_rcpf(fmaf(a, 0.47047f, 1.0f));
    float poly = t * fmaf(t, fmaf(t, 0.7478556f, -0.0958798f), 0.3480242f);
    float e = __builtin_amdgcn_exp2f(a * a * -1.4426950408889634f);
    float erfa = fmaf(-poly, e, 1.0f);
    float erfv = copysignf(erfa, v);
    return 0.5f * v * (1.0f + erfv);
}

// ---------------------------------------------------------------------------
// cumsum (chunked 3-pass) + fused h->bf16 conversion in pass 3
// ---------------------------------------------------------------------------
__global__ __launch_bounds__(256) void cumsum_pass1(const float* __restrict__ h,
                                                    float* __restrict__ partial) {
    int idx = blockIdx.x * 256 + threadIdx.x;        // (b, ch, hd)
    int hd = idx % H_; int t = idx / H_; int ch = t % CH_; int b = t / CH_;
    const float* hp = h + ((size_t)b * T_ + ch * CT_) * H_ + hd;
    float acc = 0.f;
#pragma unroll 8
    for (int tt = 0; tt < CT_; tt++) acc += hp[(size_t)tt * H_];
    partial[idx] = acc;
}

__global__ __launch_bounds__(256) void cumsum_pass2(float* __restrict__ partial) {
    int idx = blockIdx.x * 256 + threadIdx.x;        // (b, hd)
    int hd = idx % H_, b = idx / H_;
    float acc = 0.f;
#pragma unroll
    for (int ch = 0; ch < CH_; ch++) {
        size_t o = ((size_t)b * CH_ + ch) * H_ + hd;
        float v = partial[o];
        partial[o] = acc;
        acc += v;
    }
}

__global__ __launch_bounds__(256) void cumsum_pass3(const float* __restrict__ h,
                                                    const float* __restrict__ partial,
                                                    __hip_bfloat16* __restrict__ Ab) {
    int idx = blockIdx.x * 256 + threadIdx.x;        // (b, ch, hd)
    int hd = idx % H_; int t = idx / H_; int ch = t % CH_; int b = t / CH_;
    float acc = partial[idx];
    int row0 = b * T_ + ch * CT_;
    const float* hp = h + (size_t)row0 * H_ + hd;
    __hip_bfloat16* hb = Ab + (size_t)row0 * H_ + hd;
    __hip_bfloat16* pp = Ab + ((size_t)(YBASE + b * (T_ + 1) + ch * CT_ + 1)) * H_ + hd;
    if (ch == 0) Ab[((size_t)(YBASE + b * (T_ + 1))) * H_ + hd] = __float2bfloat16(0.f);
#pragma unroll 8
    for (int tt = 0; tt < CT_; tt++) {
        float hv = hp[(size_t)tt * H_];
        hb[(size_t)tt * H_] = __float2bfloat16(hv);
        acc += hv;
        pp[(size_t)tt * H_] = __float2bfloat16(acc);
    }
}

// ---------------------------------------------------------------------------
// gather span-start rows (512) + cls rows (16) into A seg2
// ---------------------------------------------------------------------------
__global__ void gather_kernel(const float* __restrict__ h,
                              const int* __restrict__ starts,
                              __hip_bfloat16* __restrict__ Ab) {
    int r = blockIdx.x;
    int src_row;
    if (r < B_ * S_) {
        int b = r / S_;
        int sv = starts[r];
        int sc = min(max(sv, 0), T_ - 1);
        src_row = b * T_ + sc;
    } else {
        int b = r - B_ * S_;
        src_row = b * T_;
    }
    __hip_bfloat16* dst = Ab + (size_t)(GBASE + r) * H_;
    for (int j = threadIdx.x; j < H_; j += 256)
        dst[j] = __float2bfloat16(h[(size_t)src_row * H_ + j]);
}

// ---------------------------------------------------------------------------
// W1 (3072x3072 fp32) -> 4 transposed bf16 panels Wt[p][n=3072][k=768]
// ---------------------------------------------------------------------------
__global__ __launch_bounds__(256) void transpose_w(const float* __restrict__ W1,
                                                   __hip_bfloat16* __restrict__ Wt) {
    __shared__ float tile[64][65];
    int n0 = blockIdx.x * 64, k0 = blockIdx.y * 64;
    int c = threadIdx.x & 63, r0 = threadIdx.x >> 6;
#pragma unroll
    for (int i = 0; i < 16; i++) {
        int r = r0 + i * 4;
        tile[r][c] = W1[(size_t)(k0 + r) * HS_ + n0 + c];
    }
    __syncthreads();
    int p = k0 / H_, kl = k0 % H_;
    __hip_bfloat16* out = Wt + (size_t)p * HS_ * H_;
#pragma unroll
    for (int i = 0; i < 16; i++) {
        int r = r0 + i * 4;
        out[(size_t)(n0 + r) * H_ + kl + c] = __float2bfloat16(tile[c][r]);
    }
}

// ---------------------------------------------------------------------------
// mega MFMA GEMM over the whole 17152-row A buffer; per-block panel/out select
// 128x128 tile, BK=32, 4 waves, 16x16x32 bf16 mfma, global_load_lds staging
// ---------------------------------------------------------------------------
__global__ __launch_bounds__(256) void mfma_gemm(const __hip_bfloat16* __restrict__ Ab,
                                                 const __hip_bfloat16* __restrict__ Wt,
                                                 __hip_bfloat16* __restrict__ XY,
                                                 float* __restrict__ ST,
                                                 float* __restrict__ CC) {
    constexpr int K = H_;
    __shared__ __hip_bfloat16 As[128 * 32];
    __shared__ __hip_bfloat16 Bs[128 * 32];
    int tid = threadIdx.x;
    int wave = tid >> 6, lane = tid & 63;
    int m0 = blockIdx.y * 128, n0 = blockIdx.x * 128;
    int wm = (wave & 1) * 64, wn = (wave >> 1) * 64;

    const __hip_bfloat16* Bt;
    if (m0 < XROWS)            Bt = Wt + (size_t)1 * HS_ * H_;  // X: h_end panel
    else if (m0 < GBASE)       Bt = Wt + (size_t)2 * HS_ * H_;  // Y: h_mean panel
    else if (m0 < GBASE + 512) Bt = Wt;                         // ST: h_start panel
    else                       Bt = Wt + (size_t)3 * HS_ * H_;  // CC: cls panel

    float4v acc[4][4] = {};

    int c1 = wave * 128 + lane;
    int c2 = c1 + 64;
    int lr = lane & 15, lq = lane >> 4;

    for (int k0 = 0; k0 < K; k0 += 32) {
        __syncthreads();
        load_lds16(Ab + (size_t)(m0 + (c1 >> 2)) * K + k0 + (c1 & 3) * 8,
                   &As[(size_t)(wave * 128) * 8]);
        load_lds16(Ab + (size_t)(m0 + (c2 >> 2)) * K + k0 + (c2 & 3) * 8,
                   &As[(size_t)(wave * 128 + 64) * 8]);
        load_lds16(Bt + (size_t)(n0 + (c1 >> 2)) * K + k0 + (c1 & 3) * 8,
                   &Bs[(size_t)(wave * 128) * 8]);
        load_lds16(Bt + (size_t)(n0 + (c2 >> 2)) * K + k0 + (c2 & 3) * 8,
                   &Bs[(size_t)(wave * 128 + 64) * 8]);
        __syncthreads();

        short8 af[4], bf[4];
        const short* Asp = (const short*)As;
        const short* Bsp = (const short*)Bs;
#pragma unroll
        for (int mi = 0; mi < 4; mi++)
            af[mi] = *(const short8*)&Asp[(wm + mi * 16 + lr) * 32 + lq * 8];
#pragma unroll
        for (int ni = 0; ni < 4; ni++)
            bf[ni] = *(const short8*)&Bsp[(wn + ni * 16 + lr) * 32 + lq * 8];
#pragma unroll
        for (int mi = 0; mi < 4; mi++)
#pragma unroll
            for (int ni = 0; ni < 4; ni++)
                acc[mi][ni] = __builtin_amdgcn_mfma_f32_16x16x32_bf16(
                    af[mi], bf[ni], acc[mi][ni], 0, 0, 0);
    }

    int col = lane & 15, rq = (lane >> 4) * 4;
#pragma unroll
    for (int mi = 0; mi < 4; mi++) {
#pragma unroll
        for (int ni = 0; ni < 4; ni++) {
#pragma unroll
            for (int r = 0; r < 4; r++) {
                int m = m0 + wm + mi * 16 + rq + r;
                int n = n0 + wn + ni * 16 + col;
                float v = acc[mi][ni][r];
                if (m < XYROWS) {
                    XY[(size_t)m * HS_ + n] = __float2bfloat16(v);
                } else if (m >= GBASE && m < GBASE + 512) {
                    ST[(size_t)(m - GBASE) * HS_ + n] = v;
                } else if (m >= GBASE + 512 && m < GBASE + 528) {
                    CC[(size_t)(m - GBASE - 512) * HS_ + n] = v;
                }
            }
        }
    }
}

// ---------------------------------------------------------------------------
// c0 = ST + CC[b] + b1, in place on ST
// ---------------------------------------------------------------------------
__global__ __launch_bounds__(256) void c0_kernel(float4* __restrict__ ST,
                                                 const float4* __restrict__ CC,
                                                 const float4* __restrict__ b1) {
    int i = blockIdx.x * 256 + threadIdx.x;  // over 512*768 float4s
    int row = i / (HS_ / 4);
    int b = row >> 5;
    int c4 = i % (HS_ / 4);
    float4 s = ST[i], c = CC[b * (HS_ / 4) + c4], bb = b1[c4];
    s.x += c.x + bb.x; s.y += c.y + bb.y; s.z += c.z + bb.z; s.w += c.w + bb.w;
    ST[i] = s;
}

// ---------------------------------------------------------------------------
// combine: one wave per (b,s,l); no LDS, no barriers
// ---------------------------------------------------------------------------
__global__ __launch_bounds__(256) void combine_kernel(
    const float* __restrict__ c0, const __hip_bfloat16* __restrict__ XY,
    const float* __restrict__ w_score, const float* __restrict__ b_score,
    const float* __restrict__ W_type,
    const int* __restrict__ starts, const int* __restrict__ ends,
    float* __restrict__ scores, float* __restrict__ tgold) {
    int bs = blockIdx.x;
    int b = bs >> 5;
    int wave = threadIdx.x >> 6, lane = threadIdx.x & 63;
    int l = blockIdx.y * 4 + wave;
    if (l >= L_) return;
    int sv = starts[bs], ev = ends[bs];
    int gi = min(max(ev - sv, 0), L_ - 1);
    int sc = min(max(sv, 0), T_ - 1);
    int p = sv + l;
    int pc = min(max(p, 0), T_ - 1);
    float invlen = 1.0f / (float)(l + 1);
    bool isg = (l == gi);

    const unsigned short* Xr = (const unsigned short*)(XY + (size_t)(b * T_ + pc) * HS_);
    const unsigned short* Yp = (const unsigned short*)(XY + (size_t)(YBASE + b * (T_ + 1) + pc + 1) * HS_);
    const unsigned short* Ys = (const unsigned short*)(XY + (size_t)(YBASE + b * (T_ + 1) + sc) * HS_);
    const float* c0r = c0 + (size_t)bs * HS_;

    float local = 0.f, t0 = 0.f, t1 = 0.f, t2 = 0.f;
#pragma unroll
    for (int j = 0; j < 6; j++) {
        int d = j * 512 + lane * 8;
        short8 xv = *(const short8*)(Xr + d);
        short8 yv = *(const short8*)(Yp + d);
        short8 sv8 = *(const short8*)(Ys + d);
        float4 ca = *(const float4*)(c0r + d);
        float4 cb = *(const float4*)(c0r + d + 4);
        float4 wa = *(const float4*)(w_score + d);
        float4 wb = *(const float4*)(w_score + d + 4);
        float cv[8] = {ca.x, ca.y, ca.z, ca.w, cb.x, cb.y, cb.z, cb.w};
        float wv[8] = {wa.x, wa.y, wa.z, wa.w, wb.x, wb.y, wb.z, wb.w};
#pragma unroll
        for (int q = 0; q < 8; q++) {
            float x = bf2f(((const unsigned short*)&xv)[q]);
            float y = bf2f(((const unsigned short*)&yv)[q]);
            float ys = bf2f(((const unsigned short*)&sv8)[q]);
            float v = fmaf(y - ys, invlen, cv[q]) + x;
            float g = gelu_exact(v);
            local = fmaf(g, wv[q], local);
            if (isg) {
                t0 = fmaf(g, W_type[(d + q) * NT_ + 0], t0);
                t1 = fmaf(g, W_type[(d + q) * NT_ + 1], t1);
                t2 = fmaf(g, W_type[(d + q) * NT_ + 2], t2);
            }
        }
    }
#pragma unroll
    for (int off = 32; off >= 1; off >>= 1) local += __shfl_down(local, off);
    if (lane == 0) scores[(size_t)bs * L_ + l] = local + b_score[0];
    if (isg) {
#pragma unroll
        for (int off = 32; off >= 1; off >>= 1) {
            t0 += __shfl_down(t0, off);
            t1 += __shfl_down(t1, off);
            t2 += __shfl_down(t2, off);
        }
        if (lane == 0) {
            tgold[bs * NT_ + 0] = t0;
            tgold[bs * NT_ + 1] = t1;
            tgold[bs * NT_ + 2] = t2;
        }
    }
}

// ---------------------------------------------------------------------------
// final loss: one block, one thread per (b,s)
// ---------------------------------------------------------------------------
__global__ __launch_bounds__(512) void loss_kernel(
    const float* __restrict__ scores, const float* __restrict__ tgold,
    const int* __restrict__ mask, const int* __restrict__ starts,
    const int* __restrict__ ends, const int* __restrict__ types,
    const float* __restrict__ b_type, float* __restrict__ out) {
    __shared__ int svl[B_];
    __shared__ float r[3][8];
    int tid = threadIdx.x;
    int b = tid / S_;
    if (tid < B_) svl[tid] = 0;
    __syncthreads();
    {
        int part = 0;
        const int* mp = mask + tid * 16;
#pragma unroll
        for (int i = 0; i < 16; i++) part += mp[i];
        atomicAdd(&svl[tid / (T_ / 16)], part);
    }
    __syncthreads();
    int vl = svl[b];
    int lt = max(1, vl - 2);
    int sv = starts[tid], ev = ends[tid];
    int gold = ev - sv;
    bool valid = (sv >= 1) && (sv <= lt) && (ev >= sv) && (ev <= lt) && (gold < L_);
    int emax = min(sv + L_ - 1, lt);
    const float* sp = scores + (size_t)tid * L_;
    float m = -1e30f;
    for (int l = 0; l < L_; l++) {
        float v = (sv + l <= emax) ? sp[l] : -1e9f;
        m = fmaxf(m, v);
    }
    float sum = 0.f;
    for (int l = 0; l < L_; l++) {
        float v = (sv + l <= emax) ? sp[l] : -1e9f;
        sum += expf(v - m);
    }
    int gi = min(max(gold, 0), L_ - 1);
    float vg = (sv + gi <= emax) ? sp[gi] : -1e9f;
    float end_loss = (m + logf(sum)) - vg;

    float t0 = tgold[tid * 3 + 0] + b_type[0];
    float t1 = tgold[tid * 3 + 1] + b_type[1];
    float t2 = tgold[tid * 3 + 2] + b_type[2];
    float tm = fmaxf(t0, fmaxf(t1, t2));
    float tsum = expf(t0 - tm) + expf(t1 - tm) + expf(t2 - tm);
    int tg = min(max(types[tid], 0), NT_ - 1);
    float tv = (tg == 0) ? t0 : ((tg == 1) ? t1 : t2);
    float type_loss = (tm + logf(tsum)) - tv;

    float ve = valid ? end_loss : 0.f;
    float vt = valid ? type_loss : 0.f;
    float vc = valid ? 1.f : 0.f;
    for (int off = 32; off >= 1; off >>= 1) {
        ve += __shfl_down(ve, off);
        vt += __shfl_down(vt, off);
        vc += __shfl_down(vc, off);
    }
    if ((tid & 63) == 0) {
        int w = tid >> 6;
        r[0][w] = ve; r[1][w] = vt; r[2][w] = vc;
    }
    __syncthreads();
    if (tid == 0) {
        float se = 0, st = 0, n = 0;
        for (int w = 0; w < 8; w++) { se += r[0][w]; st += r[1][w]; n += r[2][w]; }
        float denom = fmaxf(n, 1.f);
        out[0] = (n > 0.f) ? (se / denom + st / denom) : 0.f;
    }
}

// ---------------------------------------------------------------------------
extern "C" void kernel_launch(void* const* d_in, const int* in_sizes, int n_in,
                              void* d_out, int out_size, void* d_ws, size_t ws_size,
                              hipStream_t stream) {
    const float* h       = (const float*)d_in[0];
    const int*   mask    = (const int*)d_in[1];
    const int*   starts  = (const int*)d_in[2];
    const int*   ends    = (const int*)d_in[3];
    const int*   types   = (const int*)d_in[4];
    const float* W1      = (const float*)d_in[5];
    const float* b1      = (const float*)d_in[6];
    const float* w_score = (const float*)d_in[7];
    const float* b_score = (const float*)d_in[8];
    const float* W_type  = (const float*)d_in[9];
    const float* b_type  = (const float*)d_in[10];
    float* out = (float*)d_out;

    char* ws = (char*)d_ws;
    size_t off = 0;
    __hip_bfloat16* Ab = (__hip_bfloat16*)(ws + off); off += (size_t)AROWS * H_ * 2;
    __hip_bfloat16* XY = (__hip_bfloat16*)(ws + off); off += (size_t)XYROWS * HS_ * 2;
    __hip_bfloat16* Wt = (__hip_bfloat16*)(ws + off); off += (size_t)4 * HS_ * H_ * 2;
    float* ST     = (float*)(ws + off);               off += (size_t)512 * HS_ * 4;
    float* CC     = (float*)(ws + off);               off += (size_t)16 * HS_ * 4;
    float* scores = (float*)(ws + off);               off += (size_t)B_ * S_ * L_ * 4;
    float* tgold  = (float*)(ws + off);               off += (size_t)B_ * S_ * NT_ * 4;
    float* partial = (float*)XY;   // aliases XY; consumed by pass3 before GEMM writes XY

    hipLaunchKernelGGL(cumsum_pass1, dim3(B_ * CH_ * H_ / 256), dim3(256), 0, stream, h, partial);
    hipLaunchKernelGGL(cumsum_pass2, dim3(B_ * H_ / 256), dim3(256), 0, stream, partial);
    hipLaunchKernelGGL(cumsum_pass3, dim3(B_ * CH_ * H_ / 256), dim3(256), 0, stream, h, partial, Ab);
    hipLaunchKernelGGL(gather_kernel, dim3(B_ * S_ + B_), dim3(256), 0, stream, h, starts, Ab);
    hipLaunchKernelGGL(transpose_w, dim3(48, 48), dim3(256), 0, stream, W1, Wt);

    hipLaunchKernelGGL(mfma_gemm, dim3(24, AROWS / 128), dim3(256), 0, stream,
                       Ab, Wt, XY, ST, CC);
    hipLaunchKernelGGL(c0_kernel, dim3(512 * HS_ / 4 / 256), dim3(256), 0, stream,
                       (float4*)ST, (const float4*)CC, (const float4*)b1);
    hipLaunchKernelGGL(combine_kernel, dim3(B_ * S_, 13), dim3(256), 0, stream,
                       ST, XY, w_score, b_score, W_type, starts, ends, scores, tgold);
    hipLaunchKernelGGL(loss_kernel, dim3(1), dim3(512), 0, stream,
                       scores, tgold, mask, starts, ends, types, b_type, out);
}

// Round 4
// 364.495 us; speedup vs baseline: 5.6736x; 1.0317x over previous
//
#include <hip/hip_runtime.h>
#include <hip/hip_bf16.h>
#include <math.h>

#define B_ 16
#define T_ 512
#define H_ 768
#define S_ 32
#define L_ 50
#define NT_ 3
#define HS_ 3072
#define CH_ 8
#define CT_ 64  // T_/CH_

// A-buffer row layout (bf16, 768 cols):
//   [0, 8192)        hb   = bf16(h), row b*512+t
//   [8192, 16512)    preb = bf16(cumsum), row 8192 + b*513 + t  (8208 valid, pad to 8320)
//   [16512, 17152)   Gb   = gathered span-start rows (512) + cls rows (16), pad to 640
// XY-buffer (bf16, 3072 cols): rows 0..16399 = [X rows | Y rows], same row ids as A.
#define XROWS 8192
#define YBASE 8192
#define GBASE 16512
#define XYROWS 16400
#define AROWS 17152

typedef __attribute__((ext_vector_type(8))) short short8;
typedef __attribute__((ext_vector_type(16))) float float16v;

__device__ __forceinline__ unsigned short f2bf(float f) {
    __hip_bfloat16 b = __float2bfloat16(f);
    return *(unsigned short*)&b;
}
__device__ __forceinline__ float bf2f(unsigned short u) {
    union { unsigned int i; float f; } v; v.i = ((unsigned int)u) << 16; return v.f;
}
__device__ __forceinline__ void load_lds16(const void* g, void* l) {
    __builtin_amdgcn_global_load_lds((__attribute__((address_space(1))) void*)g,
                                     (__attribute__((address_space(3))) void*)l, 16, 0, 0);
}

// branch-free exact-gelu: Abramowitz-Stegun 3-term erf, max err 2.5e-5
__device__ __forceinline__ float gelu_exact(float v) {
    float a = fabsf(v) * 0.70710678118654752f;
    float t = __builtin_amdgcn_rcpf(fmaf(a, 0.47047f, 1.0f));
    float poly = t * fmaf(t, fmaf(t, 0.7478556f, -0.0958798f), 0.3480242f);
    float e = __builtin_amdgcn_exp2f(a * a * -1.4426950408889634f);
    float erfa = fmaf(-poly, e, 1.0f);
    float erfv = copysignf(erfa, v);
    return 0.5f * v * (1.0f + erfv);
}

// ---------------------------------------------------------------------------
// cumsum pass1: per-(b,chunk) partial sums
// ---------------------------------------------------------------------------
__global__ __launch_bounds__(256) void cumsum_pass1(const float* __restrict__ h,
                                                    float* __restrict__ partial) {
    int idx = blockIdx.x * 256 + threadIdx.x;        // (b, ch, hd)
    int hd = idx % H_; int t = idx / H_; int ch = t % CH_; int b = t / CH_;
    const float* hp = h + ((size_t)b * T_ + ch * CT_) * H_ + hd;
    float acc = 0.f;
#pragma unroll 8
    for (int tt = 0; tt < CT_; tt++) acc += hp[(size_t)tt * H_];
    partial[idx] = acc;
}

// pass3 (pass2 folded in): exclusive chunk prefix computed inline, emit bf16
// h and cumsum into the A buffer
__global__ __launch_bounds__(256) void cumsum_pass3(const float* __restrict__ h,
                                                    const float* __restrict__ partial,
                                                    __hip_bfloat16* __restrict__ Ab) {
    int idx = blockIdx.x * 256 + threadIdx.x;        // (b, ch, hd)
    int hd = idx % H_; int t = idx / H_; int ch = t % CH_; int b = t / CH_;
    float acc = 0.f;
#pragma unroll
    for (int c = 0; c < CH_; c++)
        if (c < ch) acc += partial[((size_t)b * CH_ + c) * H_ + hd];
    int row0 = b * T_ + ch * CT_;
    const float* hp = h + (size_t)row0 * H_ + hd;
    __hip_bfloat16* hb = Ab + (size_t)row0 * H_ + hd;
    __hip_bfloat16* pp = Ab + ((size_t)(YBASE + b * (T_ + 1) + ch * CT_ + 1)) * H_ + hd;
    if (ch == 0) Ab[((size_t)(YBASE + b * (T_ + 1))) * H_ + hd] = __float2bfloat16(0.f);
#pragma unroll 8
    for (int tt = 0; tt < CT_; tt++) {
        float hv = hp[(size_t)tt * H_];
        hb[(size_t)tt * H_] = __float2bfloat16(hv);
        acc += hv;
        pp[(size_t)tt * H_] = __float2bfloat16(acc);
    }
}

// ---------------------------------------------------------------------------
// gather span-start rows (512) + cls rows (16) into A seg2
// ---------------------------------------------------------------------------
__global__ void gather_kernel(const float* __restrict__ h,
                              const int* __restrict__ starts,
                              __hip_bfloat16* __restrict__ Ab) {
    int r = blockIdx.x;
    int src_row;
    if (r < B_ * S_) {
        int b = r / S_;
        int sv = starts[r];
        int sc = min(max(sv, 0), T_ - 1);
        src_row = b * T_ + sc;
    } else {
        int b = r - B_ * S_;
        src_row = b * T_;
    }
    __hip_bfloat16* dst = Ab + (size_t)(GBASE + r) * H_;
    for (int j = threadIdx.x; j < H_; j += 256)
        dst[j] = __float2bfloat16(h[(size_t)src_row * H_ + j]);
}

// ---------------------------------------------------------------------------
// W1 (3072x3072 fp32) -> 4 transposed bf16 panels Wt[p][n=3072][k=768]
// ---------------------------------------------------------------------------
__global__ __launch_bounds__(256) void transpose_w(const float* __restrict__ W1,
                                                   __hip_bfloat16* __restrict__ Wt) {
    __shared__ float tile[64][65];
    int n0 = blockIdx.x * 64, k0 = blockIdx.y * 64;
    int c = threadIdx.x & 63, r0 = threadIdx.x >> 6;
#pragma unroll
    for (int i = 0; i < 16; i++) {
        int r = r0 + i * 4;
        tile[r][c] = W1[(size_t)(k0 + r) * HS_ + n0 + c];
    }
    __syncthreads();
    int p = k0 / H_, kl = k0 % H_;
    __hip_bfloat16* out = Wt + (size_t)p * HS_ * H_;
#pragma unroll
    for (int i = 0; i < 16; i++) {
        int r = r0 + i * 4;
        out[(size_t)(n0 + r) * H_ + kl + c] = __float2bfloat16(tile[c][r]);
    }
}

// ---------------------------------------------------------------------------
// mega MFMA GEMM over the whole 17152-row A buffer.
// 128x128 tile, BK=64, 4 waves (2x2), each wave 2x2 tiles of 32x32x16 bf16.
// LDS layout per buffer: [khalf][row 128][32 k] bf16 (row stride 64B).
// grid: x = m-tile (134) fastest -> consecutive blocks share one B n-slice/XCD.
// ---------------------------------------------------------------------------
__global__ __launch_bounds__(256) void mfma_gemm(const __hip_bfloat16* __restrict__ Ab,
                                                 const __hip_bfloat16* __restrict__ Wt,
                                                 __hip_bfloat16* __restrict__ XY,
                                                 float* __restrict__ ST,
                                                 float* __restrict__ CC) {
    constexpr int K = H_;
    __shared__ __hip_bfloat16 As[2][128][32];
    __shared__ __hip_bfloat16 Bs[2][128][32];
    int tid = threadIdx.x;
    int wave = tid >> 6, lane = tid & 63;
    int m0 = blockIdx.x * 128, n0 = blockIdx.y * 128;
    int wm = (wave & 1) * 64, wn = (wave >> 1) * 64;

    const __hip_bfloat16* Bt;
    if (m0 < XROWS)            Bt = Wt + (size_t)1 * HS_ * H_;  // X: h_end panel
    else if (m0 < GBASE)       Bt = Wt + (size_t)2 * HS_ * H_;  // Y: h_mean panel
    else if (m0 < GBASE + 512) Bt = Wt;                         // ST: h_start panel
    else                       Bt = Wt + (size_t)3 * HS_ * H_;  // CC: cls panel

    float16v acc[2][2] = {};

    int l31 = lane & 31, lh = lane >> 5;

    for (int k0 = 0; k0 < K; k0 += 64) {
        __syncthreads();
#pragma unroll
        for (int i = 0; i < 4; i++) {
            int c = i * 256 + wave * 64 + lane;    // chunk id 0..1023
            int hh = c >> 9, row = (c >> 2) & 127, kc = c & 3;
            size_t go = (size_t)row * K + k0 + hh * 32 + kc * 8;
            char* ldsbase = (char*)As + (size_t)(i * 256 + wave * 64) * 16;
            load_lds16(Ab + (size_t)m0 * K + go, ldsbase);
            char* ldsbaseB = (char*)Bs + (size_t)(i * 256 + wave * 64) * 16;
            load_lds16(Bt + (size_t)n0 * K + go, ldsbaseB);
        }
        __syncthreads();

        const short* Asp = (const short*)As;
        const short* Bsp = (const short*)Bs;
#pragma unroll
        for (int kk = 0; kk < 4; kk++) {
            int hh = kk >> 1;
            int ko = (kk & 1) * 16 + lh * 8;
            short8 af[2], bf[2];
#pragma unroll
            for (int mi = 0; mi < 2; mi++)
                af[mi] = *(const short8*)&Asp[hh * 4096 + (wm + mi * 32 + l31) * 32 + ko];
#pragma unroll
            for (int ni = 0; ni < 2; ni++)
                bf[ni] = *(const short8*)&Bsp[hh * 4096 + (wn + ni * 32 + l31) * 32 + ko];
#pragma unroll
            for (int mi = 0; mi < 2; mi++)
#pragma unroll
                for (int ni = 0; ni < 2; ni++)
                    acc[mi][ni] = __builtin_amdgcn_mfma_f32_32x32x16_bf16(
                        af[mi], bf[ni], acc[mi][ni], 0, 0, 0);
        }
    }

    // epilogue: 32x32 C/D layout: col=lane&31, row=(reg&3)+8*(reg>>2)+4*(lane>>5)
#pragma unroll
    for (int mi = 0; mi < 2; mi++) {
#pragma unroll
        for (int ni = 0; ni < 2; ni++) {
            int n = n0 + wn + ni * 32 + l31;
#pragma unroll
            for (int r = 0; r < 16; r++) {
                int m = m0 + wm + mi * 32 + (r & 3) + 8 * (r >> 2) + 4 * lh;
                float v = acc[mi][ni][r];
                if (m < XYROWS) {
                    XY[(size_t)m * HS_ + n] = __float2bfloat16(v);
                } else if (m >= GBASE && m < GBASE + 512) {
                    ST[(size_t)(m - GBASE) * HS_ + n] = v;
                } else if (m >= GBASE + 512 && m < GBASE + 528) {
                    CC[(size_t)(m - GBASE - 512) * HS_ + n] = v;
                }
            }
        }
    }
}

// ---------------------------------------------------------------------------
// c0 = bf16(ST + CC[b] + b1)
// ---------------------------------------------------------------------------
__global__ __launch_bounds__(256) void c0_kernel(const float4* __restrict__ ST,
                                                 const float4* __restrict__ CC,
                                                 const float4* __restrict__ b1,
                                                 ushort4* __restrict__ c0b) {
    int i = blockIdx.x * 256 + threadIdx.x;  // over 512*768 float4s
    int row = i / (HS_ / 4);
    int b = row >> 5;
    int c4 = i % (HS_ / 4);
    float4 s = ST[i], c = CC[b * (HS_ / 4) + c4], bb = b1[c4];
    ushort4 o;
    o.x = f2bf(s.x + c.x + bb.x);
    o.y = f2bf(s.y + c.y + bb.y);
    o.z = f2bf(s.z + c.z + bb.z);
    o.w = f2bf(s.w + c.w + bb.w);
    c0b[i] = o;
}

// ---------------------------------------------------------------------------
// combine: one wave per (b,s,l); no LDS, no barriers
// ---------------------------------------------------------------------------
__global__ __launch_bounds__(256) void combine_kernel(
    const unsigned short* __restrict__ c0, const __hip_bfloat16* __restrict__ XY,
    const float* __restrict__ w_score, const float* __restrict__ b_score,
    const float* __restrict__ W_type,
    const int* __restrict__ starts, const int* __restrict__ ends,
    float* __restrict__ scores, float* __restrict__ tgold) {
    int bs = blockIdx.x;
    int b = bs >> 5;
    int wave = threadIdx.x >> 6, lane = threadIdx.x & 63;
    int l = blockIdx.y * 4 + wave;
    if (l >= L_) return;
    int sv = starts[bs], ev = ends[bs];
    int gi = min(max(ev - sv, 0), L_ - 1);
    int sc = min(max(sv, 0), T_ - 1);
    int p = sv + l;
    int pc = min(max(p, 0), T_ - 1);
    float invlen = 1.0f / (float)(l + 1);
    bool isg = (l == gi);

    const unsigned short* Xr = (const unsigned short*)(XY + (size_t)(b * T_ + pc) * HS_);
    const unsigned short* Yp = (const unsigned short*)(XY + (size_t)(YBASE + b * (T_ + 1) + pc + 1) * HS_);
    const unsigned short* Ys = (const unsigned short*)(XY + (size_t)(YBASE + b * (T_ + 1) + sc) * HS_);
    const unsigned short* c0r = c0 + (size_t)bs * HS_;

    float local = 0.f, t0 = 0.f, t1 = 0.f, t2 = 0.f;
#pragma unroll
    for (int j = 0; j < 6; j++) {
        int d = j * 512 + lane * 8;
        short8 xv = *(const short8*)(Xr + d);
        short8 yv = *(const short8*)(Yp + d);
        short8 sv8 = *(const short8*)(Ys + d);
        short8 cv8 = *(const short8*)(c0r + d);
        float4 wa = *(const float4*)(w_score + d);
        float4 wb = *(const float4*)(w_score + d + 4);
        float wv[8] = {wa.x, wa.y, wa.z, wa.w, wb.x, wb.y, wb.z, wb.w};
#pragma unroll
        for (int q = 0; q < 8; q++) {
            float x = bf2f(((const unsigned short*)&xv)[q]);
            float y = bf2f(((const unsigned short*)&yv)[q]);
            float ys = bf2f(((const unsigned short*)&sv8)[q]);
            float cv = bf2f(((const unsigned short*)&cv8)[q]);
            float v = fmaf(y - ys, invlen, cv) + x;
            float g = gelu_exact(v);
            local = fmaf(g, wv[q], local);
            if (isg) {
                t0 = fmaf(g, W_type[(d + q) * NT_ + 0], t0);
                t1 = fmaf(g, W_type[(d + q) * NT_ + 1], t1);
                t2 = fmaf(g, W_type[(d + q) * NT_ + 2], t2);
            }
        }
    }
#pragma unroll
    for (int off = 32; off >= 1; off >>= 1) local += __shfl_down(local, off);
    if (lane == 0) scores[(size_t)bs * L_ + l] = local + b_score[0];
    if (isg) {
#pragma unroll
        for (int off = 32; off >= 1; off >>= 1) {
            t0 += __shfl_down(t0, off);
            t1 += __shfl_down(t1, off);
            t2 += __shfl_down(t2, off);
        }
        if (lane == 0) {
            tgold[bs * NT_ + 0] = t0;
            tgold[bs * NT_ + 1] = t1;
            tgold[bs * NT_ + 2] = t2;
        }
    }
}

// ---------------------------------------------------------------------------
// final loss: one block, one thread per (b,s)
// ---------------------------------------------------------------------------
__global__ __launch_bounds__(512) void loss_kernel(
    const float* __restrict__ scores, const float* __restrict__ tgold,
    const int* __restrict__ mask, const int* __restrict__ starts,
    const int* __restrict__ ends, const int* __restrict__ types,
    const float* __restrict__ b_type, float* __restrict__ out) {
    __shared__ int svl[B_];
    __shared__ float r[3][8];
    int tid = threadIdx.x;
    int b = tid / S_;
    if (tid < B_) svl[tid] = 0;
    __syncthreads();
    {
        int part = 0;
        const int* mp = mask + tid * 16;
#pragma unroll
        for (int i = 0; i < 16; i++) part += mp[i];
        atomicAdd(&svl[tid / (T_ / 16)], part);
    }
    __syncthreads();
    int vl = svl[b];
    int lt = max(1, vl - 2);
    int sv = starts[tid], ev = ends[tid];
    int gold = ev - sv;
    bool valid = (sv >= 1) && (sv <= lt) && (ev >= sv) && (ev <= lt) && (gold < L_);
    int emax = min(sv + L_ - 1, lt);
    const float* sp = scores + (size_t)tid * L_;
    float m = -1e30f;
    for (int l = 0; l < L_; l++) {
        float v = (sv + l <= emax) ? sp[l] : -1e9f;
        m = fmaxf(m, v);
    }
    float sum = 0.f;
    for (int l = 0; l < L_; l++) {
        float v = (sv + l <= emax) ? sp[l] : -1e9f;
        sum += expf(v - m);
    }
    int gi = min(max(gold, 0), L_ - 1);
    float vg = (sv + gi <= emax) ? sp[gi] : -1e9f;
    float end_loss = (m + logf(sum)) - vg;

    float t0 = tgold[tid * 3 + 0] + b_type[0];
    float t1 = tgold[tid * 3 + 1] + b_type[1];
    float t2 = tgold[tid * 3 + 2] + b_type[2];
    float tm = fmaxf(t0, fmaxf(t1, t2));
    float tsum = expf(t0 - tm) + expf(t1 - tm) + expf(t2 - tm);
    int tg = min(max(types[tid], 0), NT_ - 1);
    float tv = (tg == 0) ? t0 : ((tg == 1) ? t1 : t2);
    float type_loss = (tm + logf(tsum)) - tv;

    float ve = valid ? end_loss : 0.f;
    float vt = valid ? type_loss : 0.f;
    float vc = valid ? 1.f : 0.f;
    for (int off = 32; off >= 1; off >>= 1) {
        ve += __shfl_down(ve, off);
        vt += __shfl_down(vt, off);
        vc += __shfl_down(vc, off);
    }
    if ((tid & 63) == 0) {
        int w = tid >> 6;
        r[0][w] = ve; r[1][w] = vt; r[2][w] = vc;
    }
    __syncthreads();
    if (tid == 0) {
        float se = 0, st = 0, n = 0;
        for (int w = 0; w < 8; w++) { se += r[0][w]; st += r[1][w]; n += r[2][w]; }
        float denom = fmaxf(n, 1.f);
        out[0] = (n > 0.f) ? (se / denom + st / denom) : 0.f;
    }
}

// ---------------------------------------------------------------------------
extern "C" void kernel_launch(void* const* d_in, const int* in_sizes, int n_in,
                              void* d_out, int out_size, void* d_ws, size_t ws_size,
                              hipStream_t stream) {
    const float* h       = (const float*)d_in[0];
    const int*   mask    = (const int*)d_in[1];
    const int*   starts  = (const int*)d_in[2];
    const int*   ends    = (const int*)d_in[3];
    const int*   types   = (const int*)d_in[4];
    const float* W1      = (const float*)d_in[5];
    const float* b1      = (const float*)d_in[6];
    const float* w_score = (const float*)d_in[7];
    const float* b_score = (const float*)d_in[8];
    const float* W_type  = (const float*)d_in[9];
    const float* b_type  = (const float*)d_in[10];
    float* out = (float*)d_out;

    char* ws = (char*)d_ws;
    size_t off = 0;
    __hip_bfloat16* Ab = (__hip_bfloat16*)(ws + off); off += (size_t)AROWS * H_ * 2;
    __hip_bfloat16* XY = (__hip_bfloat16*)(ws + off); off += (size_t)XYROWS * HS_ * 2;
    __hip_bfloat16* Wt = (__hip_bfloat16*)(ws + off); off += (size_t)4 * HS_ * H_ * 2;
    float* ST     = (float*)(ws + off);               off += (size_t)512 * HS_ * 4;
    float* CC     = (float*)(ws + off);               off += (size_t)16 * HS_ * 4;
    unsigned short* c0b = (unsigned short*)(ws + off); off += (size_t)512 * HS_ * 2;
    float* scores = (float*)(ws + off);               off += (size_t)B_ * S_ * L_ * 4;
    float* tgold  = (float*)(ws + off);               off += (size_t)B_ * S_ * NT_ * 4;
    float* partial = (float*)XY;   // aliases XY; consumed by pass3 before GEMM writes XY

    hipLaunchKernelGGL(cumsum_pass1, dim3(B_ * CH_ * H_ / 256), dim3(256), 0, stream, h, partial);
    hipLaunchKernelGGL(cumsum_pass3, dim3(B_ * CH_ * H_ / 256), dim3(256), 0, stream, h, partial, Ab);
    hipLaunchKernelGGL(gather_kernel, dim3(B_ * S_ + B_), dim3(256), 0, stream, h, starts, Ab);
    hipLaunchKernelGGL(transpose_w, dim3(48, 48), dim3(256), 0, stream, W1, Wt);

    hipLaunchKernelGGL(mfma_gemm, dim3(AROWS / 128, 24), dim3(256), 0, stream,
                       Ab, Wt, XY, ST, CC);
    hipLaunchKernelGGL(c0_kernel, dim3(512 * HS_ / 4 / 256), dim3(256), 0, stream,
                       (const float4*)ST, (const float4*)CC, (const float4*)b1,
                       (ushort4*)c0b);
    hipLaunchKernelGGL(combine_kernel, dim3(B_ * S_, 13), dim3(256), 0, stream,
                       c0b, XY, w_score, b_score, W_type, starts, ends, scores, tgold);
    hipLaunchKernelGGL(loss_kernel, dim3(1), dim3(512), 0, stream,
                       scores, tgold, mask, starts, ends, types, b_type, out);
}

// Round 5
// 342.964 us; speedup vs baseline: 6.0298x; 1.0628x over previous
//
#include <hip/hip_runtime.h>
#include <hip/hip_bf16.h>
#include <math.h>

#define B_ 16
#define T_ 512
#define H_ 768
#define S_ 32
#define L_ 50
#define NT_ 3
#define HS_ 3072
#define CH_ 32
#define CT_ 16  // T_/CH_

// A-buffer row layout (bf16, 768 cols):
//   [0, 8192)        hb   = bf16(h), row b*512+t
//   [8192, 16512)    preb = bf16(cumsum), row 8192 + b*513 + t  (8208 valid, pad to 8320)
//   [16512, 17152)   Gb   = gathered span-start rows (512) + cls rows (16), pad to 640
// XY-buffer (bf16, 3072 cols): rows 0..16399 = [X rows | Y rows], same row ids as A.
#define XROWS 8192
#define YBASE 8192
#define GBASE 16512
#define XYROWS 16400
#define AROWS 17152

typedef __attribute__((ext_vector_type(8))) short short8;
typedef __attribute__((ext_vector_type(16))) float float16v;

__device__ __forceinline__ unsigned short f2bf(float f) {
    __hip_bfloat16 b = __float2bfloat16(f);
    return *(unsigned short*)&b;
}
__device__ __forceinline__ float bf2f(unsigned short u) {
    union { unsigned int i; float f; } v; v.i = ((unsigned int)u) << 16; return v.f;
}
__device__ __forceinline__ void load_lds16(const void* g, void* l) {
    __builtin_amdgcn_global_load_lds((__attribute__((address_space(1))) void*)g,
                                     (__attribute__((address_space(3))) void*)l, 16, 0, 0);
}
__device__ __forceinline__ ushort4 pack4(float4 v) {
    ushort4 o; o.x = f2bf(v.x); o.y = f2bf(v.y); o.z = f2bf(v.z); o.w = f2bf(v.w);
    return o;
}

// branch-free exact-gelu: Abramowitz-Stegun 3-term erf, max err 2.5e-5
__device__ __forceinline__ float gelu_exact(float v) {
    float a = fabsf(v) * 0.70710678118654752f;
    float t = __builtin_amdgcn_rcpf(fmaf(a, 0.47047f, 1.0f));
    float poly = t * fmaf(t, fmaf(t, 0.7478556f, -0.0958798f), 0.3480242f);
    float e = __builtin_amdgcn_exp2f(a * a * -1.4426950408889634f);
    float erfa = fmaf(-poly, e, 1.0f);
    float erfv = copysignf(erfa, v);
    return 0.5f * v * (1.0f + erfv);
}

// ---------------------------------------------------------------------------
// cumsum pass1: per-(b,chunk) partial sums, float4-vectorized over hd
// ---------------------------------------------------------------------------
__global__ __launch_bounds__(256) void cumsum_pass1(const float4* __restrict__ h4,
                                                    float4* __restrict__ partial) {
    int idx = blockIdx.x * 256 + threadIdx.x;        // (b, ch, hd4)
    int hd4 = idx % 192; int t = idx / 192; int ch = t % CH_; int b = t / CH_;
    const float4* hp = h4 + ((size_t)b * T_ + ch * CT_) * 192 + hd4;
    float4 acc = {0.f, 0.f, 0.f, 0.f};
#pragma unroll
    for (int tt = 0; tt < CT_; tt++) {
        float4 v = hp[(size_t)tt * 192];
        acc.x += v.x; acc.y += v.y; acc.z += v.z; acc.w += v.w;
    }
    partial[idx] = acc;
}

// pass3 (chunk prefix folded in): emit bf16 h + bf16 cumsum into A buffer
__global__ __launch_bounds__(256) void cumsum_pass3(const float4* __restrict__ h4,
                                                    const float4* __restrict__ partial,
                                                    ushort4* __restrict__ Ab4) {
    int idx = blockIdx.x * 256 + threadIdx.x;        // (b, ch, hd4)
    int hd4 = idx % 192; int t = idx / 192; int ch = t % CH_; int b = t / CH_;
    float4 acc = {0.f, 0.f, 0.f, 0.f};
#pragma unroll
    for (int c = 0; c < CH_; c++) {
        if (c < ch) {
            float4 v = partial[((size_t)b * CH_ + c) * 192 + hd4];
            acc.x += v.x; acc.y += v.y; acc.z += v.z; acc.w += v.w;
        }
    }
    int row0 = b * T_ + ch * CT_;
    const float4* hp = h4 + (size_t)row0 * 192 + hd4;
    ushort4* hb = Ab4 + (size_t)row0 * 192 + hd4;
    ushort4* pp = Ab4 + ((size_t)(YBASE + b * (T_ + 1) + ch * CT_ + 1)) * 192 + hd4;
    if (ch == 0) {
        ushort4 z = {0, 0, 0, 0};
        Ab4[((size_t)(YBASE + b * (T_ + 1))) * 192 + hd4] = z;
    }
#pragma unroll
    for (int tt = 0; tt < CT_; tt++) {
        float4 hv = hp[(size_t)tt * 192];
        hb[(size_t)tt * 192] = pack4(hv);
        acc.x += hv.x; acc.y += hv.y; acc.z += hv.z; acc.w += hv.w;
        pp[(size_t)tt * 192] = pack4(acc);
    }
}

// ---------------------------------------------------------------------------
// gather span-start rows (512) + cls rows (16) into A seg2
// ---------------------------------------------------------------------------
__global__ void gather_kernel(const float* __restrict__ h,
                              const int* __restrict__ starts,
                              __hip_bfloat16* __restrict__ Ab) {
    int r = blockIdx.x;
    int src_row;
    if (r < B_ * S_) {
        int b = r / S_;
        int sv = starts[r];
        int sc = min(max(sv, 0), T_ - 1);
        src_row = b * T_ + sc;
    } else {
        int b = r - B_ * S_;
        src_row = b * T_;
    }
    __hip_bfloat16* dst = Ab + (size_t)(GBASE + r) * H_;
    for (int j = threadIdx.x; j < H_; j += 256)
        dst[j] = __float2bfloat16(h[(size_t)src_row * H_ + j]);
}

// ---------------------------------------------------------------------------
// W1 (3072x3072 fp32) -> 4 transposed bf16 panels Wt[p][n=3072][k=768]
// ---------------------------------------------------------------------------
__global__ __launch_bounds__(256) void transpose_w(const float* __restrict__ W1,
                                                   __hip_bfloat16* __restrict__ Wt) {
    __shared__ float tile[64][65];
    int n0 = blockIdx.x * 64, k0 = blockIdx.y * 64;
    int c = threadIdx.x & 63, r0 = threadIdx.x >> 6;
#pragma unroll
    for (int i = 0; i < 16; i++) {
        int r = r0 + i * 4;
        tile[r][c] = W1[(size_t)(k0 + r) * HS_ + n0 + c];
    }
    __syncthreads();
    int p = k0 / H_, kl = k0 % H_;
    __hip_bfloat16* out = Wt + (size_t)p * HS_ * H_;
#pragma unroll
    for (int i = 0; i < 16; i++) {
        int r = r0 + i * 4;
        out[(size_t)(n0 + r) * H_ + kl + c] = __float2bfloat16(tile[c][r]);
    }
}

// ---------------------------------------------------------------------------
// mega MFMA GEMM over the whole 17152-row A buffer.
// 128x128 tile, BK=64, 4 waves (2x2), each wave 2x2 tiles of 32x32x16 bf16.
// LDS: [hh][row 128][4 chunks of 16B], physical chunk = logical ^ ((row>>1)&3)
// (XOR swizzle -> fragment reads cover all 8 bank-groups evenly).
// grid: x = n-tile (24) fastest; 24%8==0 so n-tile j pins to XCD j%8 -> B-slices
// stay hot in each XCD's L2; A read ~once.
// ---------------------------------------------------------------------------
__global__ __launch_bounds__(256) void mfma_gemm(const __hip_bfloat16* __restrict__ Ab,
                                                 const __hip_bfloat16* __restrict__ Wt,
                                                 __hip_bfloat16* __restrict__ XY,
                                                 float* __restrict__ ST,
                                                 float* __restrict__ CC) {
    constexpr int K = H_;
    __shared__ __hip_bfloat16 As[2 * 128 * 32];
    __shared__ __hip_bfloat16 Bs[2 * 128 * 32];
    int tid = threadIdx.x;
    int wave = tid >> 6, lane = tid & 63;
    int n0 = blockIdx.x * 128, m0 = blockIdx.y * 128;
    int wm = (wave & 1) * 64, wn = (wave >> 1) * 64;

    const __hip_bfloat16* Bt;
    if (m0 < XROWS)            Bt = Wt + (size_t)1 * HS_ * H_;  // X: h_end panel
    else if (m0 < GBASE)       Bt = Wt + (size_t)2 * HS_ * H_;  // Y: h_mean panel
    else if (m0 < GBASE + 512) Bt = Wt;                         // ST: h_start panel
    else                       Bt = Wt + (size_t)3 * HS_ * H_;  // CC: cls panel

    float16v acc[2][2] = {};

    int l31 = lane & 31, lh = lane >> 5;

    for (int k0 = 0; k0 < K; k0 += 64) {
        __syncthreads();
#pragma unroll
        for (int i = 0; i < 4; i++) {
            int cid = i * 256 + wave * 64 + lane;   // 0..1023 physical 16B chunks
            int hh = cid >> 9, row = (cid >> 2) & 127, pc = cid & 3;
            int lc = pc ^ ((row >> 1) & 3);         // logical chunk this slot holds
            size_t go = (size_t)row * K + k0 + hh * 32 + lc * 8;
            load_lds16(Ab + (size_t)m0 * K + go,
                       (char*)As + (size_t)(i * 256 + wave * 64) * 16);
            load_lds16(Bt + (size_t)n0 * K + go,
                       (char*)Bs + (size_t)(i * 256 + wave * 64) * 16);
        }
        __syncthreads();

        const short* Asp = (const short*)As;
        const short* Bsp = (const short*)Bs;
#pragma unroll
        for (int kk = 0; kk < 4; kk++) {
            int hh = kk >> 1;
            int lc = 2 * (kk & 1) + lh;             // logical chunk for this frag
            short8 af[2], bf[2];
#pragma unroll
            for (int mi = 0; mi < 2; mi++) {
                int row = wm + mi * 32 + l31;
                int pc = lc ^ ((row >> 1) & 3);
                af[mi] = *(const short8*)&Asp[(hh * 512 + row * 4 + pc) * 8];
            }
#pragma unroll
            for (int ni = 0; ni < 2; ni++) {
                int row = wn + ni * 32 + l31;
                int pc = lc ^ ((row >> 1) & 3);
                bf[ni] = *(const short8*)&Bsp[(hh * 512 + row * 4 + pc) * 8];
            }
#pragma unroll
            for (int mi = 0; mi < 2; mi++)
#pragma unroll
                for (int ni = 0; ni < 2; ni++)
                    acc[mi][ni] = __builtin_amdgcn_mfma_f32_32x32x16_bf16(
                        af[mi], bf[ni], acc[mi][ni], 0, 0, 0);
        }
    }

    // epilogue: 32x32 C/D layout: col=lane&31, row=(reg&3)+8*(reg>>2)+4*(lane>>5)
#pragma unroll
    for (int mi = 0; mi < 2; mi++) {
#pragma unroll
        for (int ni = 0; ni < 2; ni++) {
            int n = n0 + wn + ni * 32 + l31;
#pragma unroll
            for (int r = 0; r < 16; r++) {
                int m = m0 + wm + mi * 32 + (r & 3) + 8 * (r >> 2) + 4 * lh;
                float v = acc[mi][ni][r];
                if (m < XYROWS) {
                    XY[(size_t)m * HS_ + n] = __float2bfloat16(v);
                } else if (m >= GBASE && m < GBASE + 512) {
                    ST[(size_t)(m - GBASE) * HS_ + n] = v;
                } else if (m >= GBASE + 512 && m < GBASE + 528) {
                    CC[(size_t)(m - GBASE - 512) * HS_ + n] = v;
                }
            }
        }
    }
}

// ---------------------------------------------------------------------------
// c0 = bf16(ST + CC[b] + b1)
// ---------------------------------------------------------------------------
__global__ __launch_bounds__(256) void c0_kernel(const float4* __restrict__ ST,
                                                 const float4* __restrict__ CC,
                                                 const float4* __restrict__ b1,
                                                 ushort4* __restrict__ c0b) {
    int i = blockIdx.x * 256 + threadIdx.x;  // over 512*768 float4s
    int row = i / (HS_ / 4);
    int b = row >> 5;
    int c4 = i % (HS_ / 4);
    float4 s = ST[i], c = CC[b * (HS_ / 4) + c4], bb = b1[c4];
    float4 v = {s.x + c.x + bb.x, s.y + c.y + bb.y, s.z + c.z + bb.z, s.w + c.w + bb.w};
    c0b[i] = pack4(v);
}

// ---------------------------------------------------------------------------
// combine: one wave per (b,s,l); no LDS, no barriers
// ---------------------------------------------------------------------------
__global__ __launch_bounds__(256) void combine_kernel(
    const unsigned short* __restrict__ c0, const __hip_bfloat16* __restrict__ XY,
    const float* __restrict__ w_score, const float* __restrict__ b_score,
    const float* __restrict__ W_type,
    const int* __restrict__ starts, const int* __restrict__ ends,
    float* __restrict__ scores, float* __restrict__ tgold) {
    int bs = blockIdx.x;
    int b = bs >> 5;
    int wave = threadIdx.x >> 6, lane = threadIdx.x & 63;
    int l = blockIdx.y * 4 + wave;
    if (l >= L_) return;
    int sv = starts[bs], ev = ends[bs];
    int gi = min(max(ev - sv, 0), L_ - 1);
    int sc = min(max(sv, 0), T_ - 1);
    int p = sv + l;
    int pc = min(max(p, 0), T_ - 1);
    float invlen = 1.0f / (float)(l + 1);
    bool isg = (l == gi);

    const unsigned short* Xr = (const unsigned short*)(XY + (size_t)(b * T_ + pc) * HS_);
    const unsigned short* Yp = (const unsigned short*)(XY + (size_t)(YBASE + b * (T_ + 1) + pc + 1) * HS_);
    const unsigned short* Ys = (const unsigned short*)(XY + (size_t)(YBASE + b * (T_ + 1) + sc) * HS_);
    const unsigned short* c0r = c0 + (size_t)bs * HS_;

    float local = 0.f, t0 = 0.f, t1 = 0.f, t2 = 0.f;
#pragma unroll
    for (int j = 0; j < 6; j++) {
        int d = j * 512 + lane * 8;
        short8 xv = *(const short8*)(Xr + d);
        short8 yv = *(const short8*)(Yp + d);
        short8 sv8 = *(const short8*)(Ys + d);
        short8 cv8 = *(const short8*)(c0r + d);
        float4 wa = *(const float4*)(w_score + d);
        float4 wb = *(const float4*)(w_score + d + 4);
        float wv[8] = {wa.x, wa.y, wa.z, wa.w, wb.x, wb.y, wb.z, wb.w};
#pragma unroll
        for (int q = 0; q < 8; q++) {
            float x = bf2f(((const unsigned short*)&xv)[q]);
            float y = bf2f(((const unsigned short*)&yv)[q]);
            float ys = bf2f(((const unsigned short*)&sv8)[q]);
            float cv = bf2f(((const unsigned short*)&cv8)[q]);
            float v = fmaf(y - ys, invlen, cv) + x;
            float g = gelu_exact(v);
            local = fmaf(g, wv[q], local);
            if (isg) {
                t0 = fmaf(g, W_type[(d + q) * NT_ + 0], t0);
                t1 = fmaf(g, W_type[(d + q) * NT_ + 1], t1);
                t2 = fmaf(g, W_type[(d + q) * NT_ + 2], t2);
            }
        }
    }
#pragma unroll
    for (int off = 32; off >= 1; off >>= 1) local += __shfl_down(local, off);
    if (lane == 0) scores[(size_t)bs * L_ + l] = local + b_score[0];
    if (isg) {
#pragma unroll
        for (int off = 32; off >= 1; off >>= 1) {
            t0 += __shfl_down(t0, off);
            t1 += __shfl_down(t1, off);
            t2 += __shfl_down(t2, off);
        }
        if (lane == 0) {
            tgold[bs * NT_ + 0] = t0;
            tgold[bs * NT_ + 1] = t1;
            tgold[bs * NT_ + 2] = t2;
        }
    }
}

// ---------------------------------------------------------------------------
// final loss: one block, one thread per (b,s)
// ---------------------------------------------------------------------------
__global__ __launch_bounds__(512) void loss_kernel(
    const float* __restrict__ scores, const float* __restrict__ tgold,
    const int* __restrict__ mask, const int* __restrict__ starts,
    const int* __restrict__ ends, const int* __restrict__ types,
    const float* __restrict__ b_type, float* __restrict__ out) {
    __shared__ int svl[B_];
    __shared__ float r[3][8];
    int tid = threadIdx.x;
    int b = tid / S_;
    if (tid < B_) svl[tid] = 0;
    __syncthreads();
    {
        int part = 0;
        const int* mp = mask + tid * 16;
#pragma unroll
        for (int i = 0; i < 16; i++) part += mp[i];
        atomicAdd(&svl[tid / (T_ / 16)], part);
    }
    __syncthreads();
    int vl = svl[b];
    int lt = max(1, vl - 2);
    int sv = starts[tid], ev = ends[tid];
    int gold = ev - sv;
    bool valid = (sv >= 1) && (sv <= lt) && (ev >= sv) && (ev <= lt) && (gold < L_);
    int emax = min(sv + L_ - 1, lt);
    const float* sp = scores + (size_t)tid * L_;
    float m = -1e30f;
    for (int l = 0; l < L_; l++) {
        float v = (sv + l <= emax) ? sp[l] : -1e9f;
        m = fmaxf(m, v);
    }
    float sum = 0.f;
    for (int l = 0; l < L_; l++) {
        float v = (sv + l <= emax) ? sp[l] : -1e9f;
        sum += expf(v - m);
    }
    int gi = min(max(gold, 0), L_ - 1);
    float vg = (sv + gi <= emax) ? sp[gi] : -1e9f;
    float end_loss = (m + logf(sum)) - vg;

    float t0 = tgold[tid * 3 + 0] + b_type[0];
    float t1 = tgold[tid * 3 + 1] + b_type[1];
    float t2 = tgold[tid * 3 + 2] + b_type[2];
    float tm = fmaxf(t0, fmaxf(t1, t2));
    float tsum = expf(t0 - tm) + expf(t1 - tm) + expf(t2 - tm);
    int tg = min(max(types[tid], 0), NT_ - 1);
    float tv = (tg == 0) ? t0 : ((tg == 1) ? t1 : t2);
    float type_loss = (tm + logf(tsum)) - tv;

    float ve = valid ? end_loss : 0.f;
    float vt = valid ? type_loss : 0.f;
    float vc = valid ? 1.f : 0.f;
    for (int off = 32; off >= 1; off >>= 1) {
        ve += __shfl_down(ve, off);
        vt += __shfl_down(vt, off);
        vc += __shfl_down(vc, off);
    }
    if ((tid & 63) == 0) {
        int w = tid >> 6;
        r[0][w] = ve; r[1][w] = vt; r[2][w] = vc;
    }
    __syncthreads();
    if (tid == 0) {
        float se = 0, st = 0, n = 0;
        for (int w = 0; w < 8; w++) { se += r[0][w]; st += r[1][w]; n += r[2][w]; }
        float denom = fmaxf(n, 1.f);
        out[0] = (n > 0.f) ? (se / denom + st / denom) : 0.f;
    }
}

// ---------------------------------------------------------------------------
extern "C" void kernel_launch(void* const* d_in, const int* in_sizes, int n_in,
                              void* d_out, int out_size, void* d_ws, size_t ws_size,
                              hipStream_t stream) {
    const float* h       = (const float*)d_in[0];
    const int*   mask    = (const int*)d_in[1];
    const int*   starts  = (const int*)d_in[2];
    const int*   ends    = (const int*)d_in[3];
    const int*   types   = (const int*)d_in[4];
    const float* W1      = (const float*)d_in[5];
    const float* b1      = (const float*)d_in[6];
    const float* w_score = (const float*)d_in[7];
    const float* b_score = (const float*)d_in[8];
    const float* W_type  = (const float*)d_in[9];
    const float* b_type  = (const float*)d_in[10];
    float* out = (float*)d_out;

    char* ws = (char*)d_ws;
    size_t off = 0;
    __hip_bfloat16* Ab = (__hip_bfloat16*)(ws + off); off += (size_t)AROWS * H_ * 2;
    __hip_bfloat16* XY = (__hip_bfloat16*)(ws + off); off += (size_t)XYROWS * HS_ * 2;
    __hip_bfloat16* Wt = (__hip_bfloat16*)(ws + off); off += (size_t)4 * HS_ * H_ * 2;
    float* ST     = (float*)(ws + off);               off += (size_t)512 * HS_ * 4;
    float* CC     = (float*)(ws + off);               off += (size_t)16 * HS_ * 4;
    unsigned short* c0b = (unsigned short*)(ws + off); off += (size_t)512 * HS_ * 2;
    float* scores = (float*)(ws + off);               off += (size_t)B_ * S_ * L_ * 4;
    float* tgold  = (float*)(ws + off);               off += (size_t)B_ * S_ * NT_ * 4;
    float4* partial = (float4*)XY;  // aliases XY; consumed by pass3 before GEMM writes XY

    hipLaunchKernelGGL(cumsum_pass1, dim3(B_ * CH_ * 192 / 256), dim3(256), 0, stream,
                       (const float4*)h, partial);
    hipLaunchKernelGGL(cumsum_pass3, dim3(B_ * CH_ * 192 / 256), dim3(256), 0, stream,
                       (const float4*)h, partial, (ushort4*)Ab);
    hipLaunchKernelGGL(gather_kernel, dim3(B_ * S_ + B_), dim3(256), 0, stream, h, starts, Ab);
    hipLaunchKernelGGL(transpose_w, dim3(48, 48), dim3(256), 0, stream, W1, Wt);

    hipLaunchKernelGGL(mfma_gemm, dim3(24, AROWS / 128), dim3(256), 0, stream,
                       Ab, Wt, XY, ST, CC);
    hipLaunchKernelGGL(c0_kernel, dim3(512 * HS_ / 4 / 256), dim3(256), 0, stream,
                       (const float4*)ST, (const float4*)CC, (const float4*)b1,
                       (ushort4*)c0b);
    hipLaunchKernelGGL(combine_kernel, dim3(B_ * S_, 13), dim3(256), 0, stream,
                       c0b, XY, w_score, b_score, W_type, starts, ends, scores, tgold);
    hipLaunchKernelGGL(loss_kernel, dim3(1), dim3(512), 0, stream,
                       scores, tgold, mask, starts, ends, types, b_type, out);
}